// Round 7
// baseline (1222.443 us; speedup 1.0000x reference)
//
#include <hip/hip_runtime.h>

// VectorQuantizer forward: inputs [64,2048,64] f32, codebook [1024,64] f32.
// Outputs concatenated in d_out (f32): quantized_ste [8388608], loss [1], indices-as-float [131072].
//
// Round 7: round-6 showed the scalar broadcast path is structurally capped:
// SMEM is out-of-order (only lgkmcnt(0) safe -> no pipelining), SGPR file
// (~102) forbids double-buffering, K$ thrashes 4 disjoint 64KB quarters ->
// ~800 cyc un-hidden stall per k-slot (VALUBusy 50%). Switch the broadcast to
// the VECTOR memory path: all-lanes-same-address global_load_dwordx4 is one
// L1 transaction broadcast on the return bus, tracked by vmcnt, which the
// compiler pipelines fine-grained against the FMAs. The base pointer is
// laundered through an opaque "+v" asm so uniformity analysis cannot
// re-scalarize the loads into s_loads (round-5 failure mode).
//
// Numerics contract (absmax 0.0 in rounds 1-6): fp32 chains
// d0:dims0-15, d1:16-31, d2:32-47, d3:48-63, combined (d0+d1)+(d2+d3);
// d2 = fl(fl(A - 2*dot) + csq[k]); per-wave scan k ascending with strict '<';
// cross-wave combine in ascending-K order with strict '<' (first min wins).

#define NROWS  131072
#define DIM    64
#define KCB    1024
#define KW     256            // k's per wave
#define RPB    64             // rows per block (one lane per row)
#define QSIZE  (NROWS * DIM)  // 8388608

__global__ __launch_bounds__(256) void vq_prep(const float* __restrict__ cb,
                                               float* __restrict__ csq,
                                               float* __restrict__ loss_slot) {
    int k = blockIdx.x * 256 + threadIdx.x;
    if (k < KCB) {
        const float* c = cb + k * DIM;
        float a0 = 0.f, a1 = 0.f, a2 = 0.f, a3 = 0.f;
        #pragma unroll
        for (int d = 0; d < 16; ++d) {
            a0 = fmaf(c[d],      c[d],      a0);
            a1 = fmaf(c[16 + d], c[16 + d], a1);
            a2 = fmaf(c[32 + d], c[32 + d], a2);
            a3 = fmaf(c[48 + d], c[48 + d], a3);
        }
        csq[k] = (a0 + a1) + (a2 + a3);
    }
    if (blockIdx.x == 0 && threadIdx.x == 0) *loss_slot = 0.f;  // zero loss accumulator every call
}

__global__ __launch_bounds__(256, 3) void vq_main(const float* __restrict__ x,
                                                  const float* __restrict__ cb,
                                                  const float* __restrict__ csq,
                                                  float* __restrict__ out_q,
                                                  float* __restrict__ out_loss,
                                                  float* __restrict__ out_idx) {
    __shared__ float s_best[4][RPB];
    __shared__ int   s_bidx[4][RPB];
    __shared__ int   s_final[RPB];
    __shared__ float s_loss[4];

    const int tid  = threadIdx.x;
    const int lane = tid & 63;
    const int wid  = tid >> 6;
    const int row  = blockIdx.x * RPB + lane;   // all 4 waves: same 64 rows

    const int kbase = wid << 8;   // this wave's K quarter

    // Opaquely-divergent base pointers: runtime-equal across lanes (hardware
    // broadcast: one L1 transaction per load), but the compiler cannot prove
    // uniformity, so the loads stay on the vector/vmcnt path.
    const float* cbp = cb + ((size_t)kbase << 6);
    const float* csp = csq + kbase;
    asm("" : "+v"(cbp));
    asm("" : "+v"(csp));

    // ---- load this thread's row into registers ----
    float xr[DIM];
    const float4* xv = reinterpret_cast<const float4*>(x + (size_t)row * DIM);
    #pragma unroll
    for (int i = 0; i < DIM / 4; ++i) {
        float4 v = xv[i];
        xr[4 * i + 0] = v.x; xr[4 * i + 1] = v.y;
        xr[4 * i + 2] = v.z; xr[4 * i + 3] = v.w;
    }

    // ---- A = sum(x^2), same chain order as the passing rounds ----
    float a0 = 0.f, a1 = 0.f, a2 = 0.f, a3 = 0.f;
    #pragma unroll
    for (int d = 0; d < 16; ++d) {
        a0 = fmaf(xr[d],      xr[d],      a0);
        a1 = fmaf(xr[16 + d], xr[16 + d], a1);
        a2 = fmaf(xr[32 + d], xr[32 + d], a2);
        a3 = fmaf(xr[48 + d], xr[48 + d], a3);
    }
    const float A = (a0 + a1) + (a2 + a3);

    // ---- scan this wave's K quarter; code row broadcast via vector loads ----
    float best = 3.4e38f;
    int   bidx = kbase;
    #pragma clang loop unroll(disable)
    for (int kk = 0; kk < KW; ++kk) {
        const float4* c4 = reinterpret_cast<const float4*>(cbp + ((size_t)kk << 6));
        float4 c[16];
        #pragma unroll
        for (int j = 0; j < 16; ++j) c[j] = c4[j];
        const float sqk = csp[kk];

        float d0 = 0.f, d1 = 0.f, d2c = 0.f, d3 = 0.f;
        #pragma unroll
        for (int j = 0; j < 4; ++j) {
            d0  = fmaf(xr[4 * j + 0],      c[j].x,      d0);
            d0  = fmaf(xr[4 * j + 1],      c[j].y,      d0);
            d0  = fmaf(xr[4 * j + 2],      c[j].z,      d0);
            d0  = fmaf(xr[4 * j + 3],      c[j].w,      d0);
            d1  = fmaf(xr[16 + 4 * j + 0], c[4 + j].x,  d1);
            d1  = fmaf(xr[16 + 4 * j + 1], c[4 + j].y,  d1);
            d1  = fmaf(xr[16 + 4 * j + 2], c[4 + j].z,  d1);
            d1  = fmaf(xr[16 + 4 * j + 3], c[4 + j].w,  d1);
            d2c = fmaf(xr[32 + 4 * j + 0], c[8 + j].x,  d2c);
            d2c = fmaf(xr[32 + 4 * j + 1], c[8 + j].y,  d2c);
            d2c = fmaf(xr[32 + 4 * j + 2], c[8 + j].z,  d2c);
            d2c = fmaf(xr[32 + 4 * j + 3], c[8 + j].w,  d2c);
            d3  = fmaf(xr[48 + 4 * j + 0], c[12 + j].x, d3);
            d3  = fmaf(xr[48 + 4 * j + 1], c[12 + j].y, d3);
            d3  = fmaf(xr[48 + 4 * j + 2], c[12 + j].z, d3);
            d3  = fmaf(xr[48 + 4 * j + 3], c[12 + j].w, d3);
        }
        const float dot = (d0 + d1) + (d2c + d3);
        const float tt  = A - 2.0f * dot;    // 2*dot exact; one rounding
        const float dd  = tt + sqk;          // second rounding, ref expr
        if (dd < best) { best = dd; bidx = kbase + kk; }  // strict '<': first min wins
    }

    s_best[wid][lane] = best;
    s_bidx[wid][lane] = bidx;
    __syncthreads();

    // ---- cross-wave combine, ascending-K order, strict '<' (first min wins) ----
    if (tid < RPB) {
        float b = s_best[0][tid];
        int   i = s_bidx[0][tid];
        #pragma unroll
        for (int w = 1; w < 4; ++w) {
            const float bw = s_best[w][tid];
            const int   iw = s_bidx[w][tid];
            if (bw < b) { b = bw; i = iw; }
        }
        s_final[tid] = i;
        out_idx[blockIdx.x * RPB + tid] = (float)i;
    }
    __syncthreads();

    // ---- epilogue: coalesced STE write + loss partial ----
    const size_t base = (size_t)blockIdx.x * RPB * DIM;
    float lsum = 0.f;
    #pragma unroll 4
    for (int i = tid; i < RPB * DIM; i += 256) {
        const int r = i >> 6;
        const int d = i & 63;
        const int kb = s_final[r];
        const float q  = cb[(size_t)kb * DIM + d];
        const float xe = x[base + i];
        out_q[base + i] = xe + (q - xe);     // STE forward, ref's rounding
        const float df = q - xe;
        lsum = fmaf(df, df, lsum);
    }
    #pragma unroll
    for (int off = 32; off; off >>= 1) lsum += __shfl_down(lsum, off, 64);
    if (lane == 0) s_loss[wid] = lsum;
    __syncthreads();
    if (tid == 0) {
        const float tot = (s_loss[0] + s_loss[1]) + (s_loss[2] + s_loss[3]);
        atomicAdd(out_loss, tot * (1.25f / 8388608.0f));  // (q + 0.25*e) / count
    }
}

extern "C" void kernel_launch(void* const* d_in, const int* in_sizes, int n_in,
                              void* d_out, int out_size, void* d_ws, size_t ws_size,
                              hipStream_t stream) {
    const float* x  = (const float*)d_in[0];   // 8388608
    const float* cb = (const float*)d_in[1];   // 65536
    float* out      = (float*)d_out;
    float* out_loss = out + QSIZE;             // [8388608]
    float* out_idx  = out + QSIZE + 1;         // [8388609 .. 8519680]
    float* csq      = (float*)d_ws;            // 1024 floats scratch

    vq_prep<<<4, 256, 0, stream>>>(cb, csq, out_loss);
    vq_main<<<NROWS / RPB, 256, 0, stream>>>(x, cb, csq, out, out_loss, out_idx);
}

// Round 8
// 292.825 us; speedup vs baseline: 4.1746x; 4.1746x over previous
//
#include <hip/hip_runtime.h>

// VectorQuantizer forward: inputs [64,2048,64] f32, codebook [1024,64] f32.
// Outputs (f32, concat): quantized_ste [8388608], loss [1], indices-as-float [131072].
//
// Round 8: rounds 4-7 proved every 1-float-per-FMA broadcast path is
// delivery-bound (LDS 660us / SMEM 301us / same-addr vector 1222us). Fix the
// RATIO instead: register-blocked GEMM, thread tile 8 rows x 4 codes ->
// 32 FMAs per 12 LDS floats. DS ~36 cyc < VALU ~70 cyc per k-step => VALU-bound.
//
// Numerics: A-norm uses the exact 16-dim partial chains of rounds 1-6
// (quarter-row staging threads). d2 = fl(fl(A - 2*dot) + csq[k]) preserved.
// Argmin via u64 key (d2_bits<<32 | idx): d2>0 => monotone; min = first-index-
// wins among grid-ties, order-free. Dot k-chain is now sequential 0..63
// (error ~1e-8 << 7.6e-6 grid spacing of A-2dot at d2~64).

#define NROWS  131072
#define DIM    64
#define KCB    1024
#define MT     64             // rows per block
#define NT     128            // codes per LDS tile
#define NTILES (KCB / NT)     // 8
#define QSIZE  (NROWS * DIM)  // 8388608

__global__ __launch_bounds__(256) void vq_prep(const float* __restrict__ cb,
                                               float* __restrict__ csq,
                                               float* __restrict__ loss_slot) {
    int k = blockIdx.x * 256 + threadIdx.x;
    if (k < KCB) {
        const float* c = cb + k * DIM;
        float a0 = 0.f, a1 = 0.f, a2 = 0.f, a3 = 0.f;
        #pragma unroll
        for (int d = 0; d < 16; ++d) {
            a0 = fmaf(c[d],      c[d],      a0);
            a1 = fmaf(c[16 + d], c[16 + d], a1);
            a2 = fmaf(c[32 + d], c[32 + d], a2);
            a3 = fmaf(c[48 + d], c[48 + d], a3);
        }
        csq[k] = (a0 + a1) + (a2 + a3);
    }
    if (blockIdx.x == 0 && threadIdx.x == 0) *loss_slot = 0.f;  // zero loss accumulator every call
}

__global__ __launch_bounds__(256, 3) void vq_main(const float* __restrict__ x,
                                                  const float* __restrict__ cb,
                                                  const float* __restrict__ csq,
                                                  float* __restrict__ out_q,
                                                  float* __restrict__ out_loss,
                                                  float* __restrict__ out_idx) {
    __shared__ float sA[DIM][MT];        // 16 KB, dim-major (no pad: 2-way max on reads = free)
    __shared__ float sB[DIM][NT];        // 32 KB, dim-major
    __shared__ float sPart[MT][4];       // A-norm 16-dim partial chains
    __shared__ float sAn[MT];            // A-norms (exact round-1..6 values)
    __shared__ unsigned long long sWK[4][MT];  // per-wave argmin keys
    __shared__ int   sFinal[MT];
    __shared__ float sLoss[4];

    const int tid  = threadIdx.x;
    const int lane = tid & 63;
    const int wid  = tid >> 6;
    const int mg   = tid & 7;        // row group: rows 8*mg .. 8*mg+7
    const int ng   = tid >> 3;       // code group: codes 4*ng .. 4*ng+3 of tile
    const size_t rowbase = (size_t)blockIdx.x * MT;

    // ---- stage A (x-tile) dim-major + exact A-norm partials ----
    {
        const int r = tid >> 2;      // 0..63
        const int q = tid & 3;       // dim quarter 16q..16q+15
        const float4* gx = reinterpret_cast<const float4*>(
            x + (rowbase + (size_t)r) * DIM + 16 * q);
        float4 v0 = gx[0], v1 = gx[1], v2 = gx[2], v3 = gx[3];
        float t[16] = {v0.x, v0.y, v0.z, v0.w, v1.x, v1.y, v1.z, v1.w,
                       v2.x, v2.y, v2.z, v2.w, v3.x, v3.y, v3.z, v3.w};
        float aq = 0.f;
        #pragma unroll
        for (int j = 0; j < 16; ++j) aq = fmaf(t[j], t[j], aq);  // exact chain q
        sPart[r][q] = aq;
        #pragma unroll
        for (int j = 0; j < 16; ++j) sA[16 * q + j][r] = t[j];   // dim-major scatter
    }
    __syncthreads();
    if (tid < MT)
        sAn[tid] = (sPart[tid][0] + sPart[tid][1]) + (sPart[tid][2] + sPart[tid][3]);
    __syncthreads();

    float asq[8];
    #pragma unroll
    for (int i = 0; i < 8; ++i) asq[i] = sAn[8 * mg + i];

    unsigned long long key[8];
    #pragma unroll
    for (int i = 0; i < 8; ++i) key[i] = ~0ull;

    // ---- N-tile loop ----
    for (int t = 0; t < NTILES; ++t) {
        __syncthreads();   // protect previous tile's sB readers
        {
            const int n = tid >> 1;      // 0..127
            const int h = tid & 1;       // dim half 32h..32h+31
            const float4* gc = reinterpret_cast<const float4*>(
                cb + ((size_t)(t * NT + n)) * DIM + 32 * h);
            float4 u[8];
            #pragma unroll
            for (int j = 0; j < 8; ++j) u[j] = gc[j];
            #pragma unroll
            for (int j = 0; j < 8; ++j) {
                sB[32 * h + 4 * j + 0][n] = u[j].x;
                sB[32 * h + 4 * j + 1][n] = u[j].y;
                sB[32 * h + 4 * j + 2][n] = u[j].z;
                sB[32 * h + 4 * j + 3][n] = u[j].w;
            }
        }
        __syncthreads();

        float acc[8][4];
        #pragma unroll
        for (int i = 0; i < 8; ++i)
            #pragma unroll
            for (int j = 0; j < 4; ++j) acc[i][j] = 0.f;

        #pragma unroll 4
        for (int k = 0; k < DIM; ++k) {
            const float4 a0 = *reinterpret_cast<const float4*>(&sA[k][8 * mg]);
            const float4 a1 = *reinterpret_cast<const float4*>(&sA[k][8 * mg + 4]);
            const float4 bv = *reinterpret_cast<const float4*>(&sB[k][4 * ng]);
            const float a[8] = {a0.x, a0.y, a0.z, a0.w, a1.x, a1.y, a1.z, a1.w};
            const float b[4] = {bv.x, bv.y, bv.z, bv.w};
            #pragma unroll
            for (int i = 0; i < 8; ++i)
                #pragma unroll
                for (int j = 0; j < 4; ++j)
                    acc[i][j] = fmaf(a[i], b[j], acc[i][j]);
        }

        // ---- tail: d2 + key update (ref expression roundings preserved) ----
        #pragma unroll
        for (int j = 0; j < 4; ++j) {
            const int n = t * NT + 4 * ng + j;
            const float cs = csq[n];
            #pragma unroll
            for (int i = 0; i < 8; ++i) {
                const float tt = asq[i] - 2.0f * acc[i][j];  // one rounding (2*acc exact)
                const float dd = tt + cs;                    // second rounding
                const unsigned long long kk =
                    ((unsigned long long)__float_as_uint(dd) << 32) | (unsigned)n;
                key[i] = kk < key[i] ? kk : key[i];
            }
        }
    }

    // ---- cross-lane argmin (u64 keys, order-free, first-index-wins) ----
    #pragma unroll
    for (int i = 0; i < 8; ++i) {
        unsigned long long kk = key[i];
        #pragma unroll
        for (int m = 8; m <= 32; m <<= 1) {
            unsigned long long o = __shfl_xor(kk, m, 64);
            kk = o < kk ? o : kk;
        }
        key[i] = kk;
    }
    if (lane < 8) {
        #pragma unroll
        for (int i = 0; i < 8; ++i) sWK[wid][8 * lane + i] = key[i];
    }
    __syncthreads();
    if (tid < MT) {
        unsigned long long b0 = sWK[0][tid], b1 = sWK[1][tid];
        unsigned long long b2 = sWK[2][tid], b3 = sWK[3][tid];
        unsigned long long m01 = b0 < b1 ? b0 : b1;
        unsigned long long m23 = b2 < b3 ? b2 : b3;
        unsigned long long fk  = m01 < m23 ? m01 : m23;
        const int idx = (int)(unsigned)fk;
        sFinal[tid] = idx;
        out_idx[rowbase + tid] = (float)idx;
    }
    __syncthreads();

    // ---- epilogue: coalesced STE write + loss partial ----
    const size_t base = rowbase * DIM;
    float lsum = 0.f;
    #pragma unroll 4
    for (int i = tid; i < MT * DIM; i += 256) {
        const int r = i >> 6;
        const int d = i & 63;
        const int kb = sFinal[r];            // wave-uniform per iteration
        const float q  = cb[(size_t)kb * DIM + d];
        const float xe = x[base + i];
        out_q[base + i] = xe + (q - xe);     // STE forward, ref's rounding
        const float df = q - xe;
        lsum = fmaf(df, df, lsum);
    }
    #pragma unroll
    for (int off = 32; off; off >>= 1) lsum += __shfl_down(lsum, off, 64);
    if (lane == 0) sLoss[wid] = lsum;
    __syncthreads();
    if (tid == 0) {
        const float tot = (sLoss[0] + sLoss[1]) + (sLoss[2] + sLoss[3]);
        atomicAdd(out_loss, tot * (1.25f / 8388608.0f));  // (q + 0.25*e) / count
    }
}

extern "C" void kernel_launch(void* const* d_in, const int* in_sizes, int n_in,
                              void* d_out, int out_size, void* d_ws, size_t ws_size,
                              hipStream_t stream) {
    const float* x  = (const float*)d_in[0];   // 8388608
    const float* cb = (const float*)d_in[1];   // 65536
    float* out      = (float*)d_out;
    float* out_loss = out + QSIZE;             // [8388608]
    float* out_idx  = out + QSIZE + 1;         // [8388609 .. 8519680]
    float* csq      = (float*)d_ws;            // 1024 floats scratch

    vq_prep<<<4, 256, 0, stream>>>(cb, csq, out_loss);
    vq_main<<<NROWS / MT, 256, 0, stream>>>(x, cb, csq, out, out_loss, out_idx);
}